// Round 1
// baseline (178.022 us; speedup 1.0000x reference)
//
#include <hip/hip_runtime.h>
#include <hip/hip_bf16.h>

// Problem dims (fixed by reference):
//   N=2048 nodes, E=64 (node emb), H=64 (hidden), B=32, T=48, C=32
//   gate[n] = sigmoid( relu( concat(u[n],d[n]) @ W1 + b1 ) @ W2 + b2 )
//   out[b,t,n,c] = hist[b,t,n,c] * gate[n]

#define N_NODES 2048
#define E_DIM   64
#define H_DIM   64
#define C_DIM   32

// One wave (64 threads) per node. Thread h computes hidden[h], then a
// 64-lane shuffle reduction produces the H->1 dot product.
__global__ void gate_kernel(const float* __restrict__ u,
                            const float* __restrict__ d,
                            const float* __restrict__ W1,   // [128,64] row-major
                            const float* __restrict__ b1,   // [64]
                            const float* __restrict__ W2,   // [64]
                            const float* __restrict__ b2,   // [1]
                            float* __restrict__ gate) {     // [N]
    const int n = blockIdx.x;
    const int h = threadIdx.x;  // 0..63

    __shared__ float feat[2 * E_DIM];
    feat[h]          = u[n * E_DIM + h];
    feat[h + E_DIM]  = d[n * E_DIM + h];
    __syncthreads();

    float acc = b1[h];
#pragma unroll
    for (int k = 0; k < 2 * E_DIM; ++k) {
        // W1[k*64 + h]: consecutive h across lanes -> coalesced
        acc = fmaf(feat[k], W1[k * H_DIM + h], acc);
    }
    float hid = fmaxf(acc, 0.0f);
    float p = hid * W2[h];

    // 64-lane wave reduction
#pragma unroll
    for (int off = 32; off > 0; off >>= 1)
        p += __shfl_down(p, off);

    if (h == 0) {
        float x = p + b2[0];
        gate[n] = 1.0f / (1.0f + expf(-x));
    }
}

// float4-vectorized broadcast multiply. Each float4 (4 consecutive c's,
// C=32 % 4 == 0) lies within one node row, so n = (i4 >> 3) & (N-1).
__global__ void mul_kernel(const float* __restrict__ hist,
                           const float* __restrict__ gate,
                           float* __restrict__ out,
                           long total4) {
    long i = (long)blockIdx.x * blockDim.x + threadIdx.x;
    const long stride = (long)gridDim.x * blockDim.x;
    for (; i < total4; i += stride) {
        float4 v = reinterpret_cast<const float4*>(hist)[i];
        const int n = (int)((i >> 3) & (N_NODES - 1));
        const float g = gate[n];
        v.x *= g; v.y *= g; v.z *= g; v.w *= g;
        reinterpret_cast<float4*>(out)[i] = v;
    }
}

extern "C" void kernel_launch(void* const* d_in, const int* in_sizes, int n_in,
                              void* d_out, int out_size, void* d_ws, size_t ws_size,
                              hipStream_t stream) {
    const float* u    = (const float*)d_in[0];  // [N,E]
    const float* dd   = (const float*)d_in[1];  // [N,E]
    const float* hist = (const float*)d_in[2];  // [B,T,N,C]
    const float* W1   = (const float*)d_in[3];  // [2E,H]
    const float* b1   = (const float*)d_in[4];  // [H]
    const float* W2   = (const float*)d_in[5];  // [H,1]
    const float* b2   = (const float*)d_in[6];  // [1]
    float* out  = (float*)d_out;
    float* gate = (float*)d_ws;                 // N floats = 8 KB scratch

    // 1) per-node gate: 2048 blocks x 1 wave
    gate_kernel<<<N_NODES, 64, 0, stream>>>(u, dd, W1, b1, W2, b2, gate);

    // 2) broadcast multiply: memory-bound grid-stride, float4
    const long total4 = (long)out_size / 4;     // 25,165,824 float4s
    mul_kernel<<<2048, 256, 0, stream>>>(hist, gate, out, total4);
}

// Round 2
// 157.808 us; speedup vs baseline: 1.1281x; 1.1281x over previous
//
#include <hip/hip_runtime.h>
#include <hip/hip_bf16.h>

// Problem dims (fixed by reference):
//   N=2048 nodes, E=64 (node emb), H=64 (hidden), B=32, T=48, C=32
//   gate[n] = sigmoid( relu( concat(u[n],d[n]) @ W1 + b1 ) @ W2 + b2 )
//   out[b,t,n,c] = hist[b,t,n,c] * gate[n]

#define N_NODES 2048
#define E_DIM   64
#define H_DIM   64
#define C_DIM   32

typedef float f32x4 __attribute__((ext_vector_type(4)));

// One wave (64 threads) per node. Thread h computes hidden[h], then a
// 64-lane shuffle reduction produces the H->1 dot product.
__global__ void gate_kernel(const float* __restrict__ u,
                            const float* __restrict__ d,
                            const float* __restrict__ W1,   // [128,64] row-major
                            const float* __restrict__ b1,   // [64]
                            const float* __restrict__ W2,   // [64]
                            const float* __restrict__ b2,   // [1]
                            float* __restrict__ gate) {     // [N]
    const int n = blockIdx.x;
    const int h = threadIdx.x;  // 0..63

    __shared__ float feat[2 * E_DIM];
    feat[h]          = u[n * E_DIM + h];
    feat[h + E_DIM]  = d[n * E_DIM + h];
    __syncthreads();

    float acc = b1[h];
#pragma unroll
    for (int k = 0; k < 2 * E_DIM; ++k) {
        // W1[k*64 + h]: consecutive h across lanes -> coalesced
        acc = fmaf(feat[k], W1[k * H_DIM + h], acc);
    }
    float hid = fmaxf(acc, 0.0f);
    float p = hid * W2[h];

    // 64-lane wave reduction
#pragma unroll
    for (int off = 32; off > 0; off >>= 1)
        p += __shfl_down(p, off);

    if (h == 0) {
        float x = p + b2[0];
        gate[n] = 1.0f / (1.0f + expf(-x));
    }
}

// Streaming broadcast multiply.
// Each thread handles 4 float4s at stride = gridDim*blockDim (6,291,456),
// which is a multiple of 8*N_NODES = 16384, so all 4 chunks share the SAME
// node index -> one gate load per thread. Non-temporal loads/stores skip
// L2 write-allocate/pollution (805 MB streaming, zero reuse).
__global__ __launch_bounds__(256) void mul_kernel(const f32x4* __restrict__ hist4,
                                                  const float* __restrict__ gate,
                                                  f32x4* __restrict__ out4,
                                                  long total4) {
    const long base   = (long)blockIdx.x * blockDim.x + threadIdx.x;
    const long stride = (long)gridDim.x * blockDim.x;  // multiple of 16384

    const long i0 = base;
    const long i1 = base + stride;
    const long i2 = base + 2 * stride;
    const long i3 = base + 3 * stride;

    // Independent loads issued back-to-back (4 x 16B in flight per lane).
    f32x4 v0, v1, v2, v3;
    bool p0 = i0 < total4, p1 = i1 < total4, p2 = i2 < total4, p3 = i3 < total4;
    if (p0) v0 = __builtin_nontemporal_load(hist4 + i0);
    if (p1) v1 = __builtin_nontemporal_load(hist4 + i1);
    if (p2) v2 = __builtin_nontemporal_load(hist4 + i2);
    if (p3) v3 = __builtin_nontemporal_load(hist4 + i3);

    const float g = gate[(int)((base >> 3) & (N_NODES - 1))];

    if (p0) __builtin_nontemporal_store(v0 * g, out4 + i0);
    if (p1) __builtin_nontemporal_store(v1 * g, out4 + i1);
    if (p2) __builtin_nontemporal_store(v2 * g, out4 + i2);
    if (p3) __builtin_nontemporal_store(v3 * g, out4 + i3);
}

extern "C" void kernel_launch(void* const* d_in, const int* in_sizes, int n_in,
                              void* d_out, int out_size, void* d_ws, size_t ws_size,
                              hipStream_t stream) {
    const float* u    = (const float*)d_in[0];  // [N,E]
    const float* dd   = (const float*)d_in[1];  // [N,E]
    const float* hist = (const float*)d_in[2];  // [B,T,N,C]
    const float* W1   = (const float*)d_in[3];  // [2E,H]
    const float* b1   = (const float*)d_in[4];  // [H]
    const float* W2   = (const float*)d_in[5];  // [H,1]
    const float* b2   = (const float*)d_in[6];  // [1]
    float* out  = (float*)d_out;
    float* gate = (float*)d_ws;                 // N floats = 8 KB scratch

    // 1) per-node gate: 2048 blocks x 1 wave
    gate_kernel<<<N_NODES, 64, 0, stream>>>(u, dd, W1, b1, W2, b2, gate);

    // 2) broadcast multiply: exact-cover grid, 4 float4s/thread
    const long total4 = (long)out_size / 4;            // 25,165,824
    const long threads_needed = (total4 + 3) / 4;      // 6,291,456
    const int  blocks = (int)((threads_needed + 255) / 256);  // 24,576
    mul_kernel<<<blocks, 256, 0, stream>>>((const f32x4*)hist, gate,
                                           (f32x4*)out, total4);
}